// Round 1
// 2409.234 us; speedup vs baseline: 1.0476x; 1.0476x over previous
//
#include <hip/hip_runtime.h>

// LightGCN propagation: ego = concat(user,item); 3x { ego = A@ego; acc += ego }
// Round-3: replace the 920us random-scatter CSR build (15x write amplification,
// WRITE_SIZE 1.19GB vs 77MB payload) with a bucketed split counting sort:
//   A1 per-block bucket histogram (fused w/ global row hist)
//   A2 scan of count matrix -> per-(block,bucket) offsets
//   A3 chunked scatter into bucket-ordered staging (contiguous ~256B chunks)
//   B  per-bucket workgroup: LDS cursors, scatter into 150KB XCD-local region
// Staging aliases acc+ego1 (dead after B), so T0_NEED (194.01MB) <= old T1B_NEED.

typedef unsigned short u16;
typedef unsigned int   u32;

#define USER_ELEMS   (200000 * 64)
#define N_NODES      300000
#define EMB          64
#define NNZ          12800000
#define TOTAL_ELEMS  (N_NODES * EMB)     // 19,200,000
#define SCAN_CHUNK   2048
#define SCAN_NB      147                 // ceil(300000 / 2048)

// ---- bucket build (T0) geometry ----
#define NBUCK    512
#define ROWS_PB  586                     // 512*586 = 300,032 >= 300,000
#define EPB      32768                   // edges per block in passes A1/A3
#define NB_A     391                     // ceil(NNZ / EPB)
#define CNT_LEN  (NBUCK * NB_A)          // 200,192
#define SCAN2_NB 98                      // ceil(200192 / 2048)

// workspace region sizes (bytes)
#define FLAGS_SZ   256ULL
#define ACC_SZ     76800000ULL           // fp32 acc
#define EGO_SZ     38400000ULL           // bf16 ego
#define RP_SZ      1200128ULL            // row_ptr (300,032 ints)
#define BS_SZ      1024ULL
#define CNTM_SZ    800768ULL             // CNT_LEN * 4
#define COL_SZ     51200000ULL
#define VALSORT_SZ 25600000ULL
#define BIG_SZ     115200000ULL          // max(ecol+eval=76.8M, acc+ego1=115.2M)
#define PERM_SZ    51200000ULL
#define LAYER_SZ   76800000ULL

#define T0_NEED (FLAGS_SZ + RP_SZ + 4*BS_SZ + CNTM_SZ + COL_SZ + VALSORT_SZ + BIG_SZ) // 194,005,248
#define T2_NEED (FLAGS_SZ + ACC_SZ + EGO_SZ + 2*RP_SZ + 2*BS_SZ + PERM_SZ)            // 168,802,560
// T3 fallback below T2.

__device__ __forceinline__ float bf2f(u16 b) {
    return __uint_as_float(((u32)b) << 16);
}
__device__ __forceinline__ u16 f2bf(float f) {
    u32 u = __float_as_uint(f);
    u32 r = (u + 0x7fffu + ((u >> 16) & 1u)) >> 16;   // round-to-nearest-even
    return (u16)r;
}

// ---------------- dtype detection ----------------
__global__ void k_detect(const u16* __restrict__ emb, const u16* __restrict__ vals,
                         int* __restrict__ flags) {
    int lane = threadIdx.x;                 // 64 threads, 1 wave
    u16 a = emb[lane * 2];
    int ea = (a >> 7) & 0xFF;
    bool pa = (ea >= 0x60 && ea <= 0x7E);
    unsigned long long ba = __ballot(pa);
    u16 b = vals[lane * 2];
    int eb = (b >> 7) & 0xFF;
    bool pb = (eb >= 0x60 && eb <= 0x7E);
    unsigned long long bb = __ballot(pb);
    if (lane == 0) {
        flags[0] = (__popcll(ba) >= 56) ? 0 : 1;   // 0 = bf16, 1 = fp32
        flags[1] = (__popcll(bb) >= 56) ? 0 : 1;
    }
}

// ---------------- init: ego0 (bf16) + acc (fp32) ----------------
__global__ void k_init(const void* __restrict__ user, const void* __restrict__ item,
                       const int* __restrict__ flags,
                       u16* __restrict__ ego, float* __restrict__ acc) {
    int t = blockIdx.x * blockDim.x + threadIdx.x;
    int e = t * 4;
    if (e >= TOTAL_ELEMS) return;
    float4 f;
    if (flags[0]) {
        const float* src = (e < USER_ELEMS) ? ((const float*)user + e)
                                            : ((const float*)item + (e - USER_ELEMS));
        f = *(const float4*)src;
    } else {
        const u16* src = (e < USER_ELEMS) ? ((const u16*)user + e)
                                          : ((const u16*)item + (e - USER_ELEMS));
        ushort4 v = *(const ushort4*)src;
        f.x = bf2f(v.x); f.y = bf2f(v.y); f.z = bf2f(v.z); f.w = bf2f(v.w);
    }
    ushort4 o;
    o.x = f2bf(f.x); o.y = f2bf(f.y); o.z = f2bf(f.z); o.w = f2bf(f.w);
    *(ushort4*)(ego + e) = o;
    *(float4*)(acc + e) = f;
}

// ---------------- generic 3-phase exclusive scan ----------------
__global__ void k_scan_reduce(const int* __restrict__ cnt, int* __restrict__ blockSums,
                              int n) {
    __shared__ int s[256];
    int b = blockIdx.x;
    int base = b * SCAN_CHUNK + threadIdx.x;
    int sum = 0;
#pragma unroll
    for (int k = 0; k < 8; ++k) {
        int i = base + k * 256;
        if (i < n) sum += cnt[i];
    }
    s[threadIdx.x] = sum;
    __syncthreads();
    for (int off = 128; off > 0; off >>= 1) {
        if (threadIdx.x < (unsigned)off) s[threadIdx.x] += s[threadIdx.x + off];
        __syncthreads();
    }
    if (threadIdx.x == 0) blockSums[b] = s[0];
}

__global__ void k_scan_block(const int* __restrict__ blockSums, int* __restrict__ blockOffs,
                             int nb) {
    __shared__ int s[256];
    int x = (threadIdx.x < nb) ? blockSums[threadIdx.x] : 0;
    s[threadIdx.x] = x;
    __syncthreads();
    for (int off = 1; off < 256; off <<= 1) {
        int t = 0;
        if (threadIdx.x >= (unsigned)off) t = s[threadIdx.x - off];
        __syncthreads();
        s[threadIdx.x] += t;
        __syncthreads();
    }
    if (threadIdx.x < nb) blockOffs[threadIdx.x] = s[threadIdx.x] - x;
}

// In-place safe (each thread reads its 8 values before writing them).
// cursor2 may be null; may alias cnt.
__global__ void k_scan_down(const int* cnt, const int* __restrict__ blockOffs,
                            int* __restrict__ out, int* cursor2,
                            int n, int total, int writeTotal) {
    __shared__ int s[256];
    int b = blockIdx.x;
    int base = b * SCAN_CHUNK + threadIdx.x * 8;
    int v[8];
    int tsum = 0;
#pragma unroll
    for (int k = 0; k < 8; ++k) {
        int i = base + k;
        v[k] = (i < n) ? cnt[i] : 0;
        tsum += v[k];
    }
    s[threadIdx.x] = tsum;
    __syncthreads();
    for (int off = 1; off < 256; off <<= 1) {
        int t = 0;
        if (threadIdx.x >= (unsigned)off) t = s[threadIdx.x - off];
        __syncthreads();
        s[threadIdx.x] += t;
        __syncthreads();
    }
    int running = blockOffs[b] + (s[threadIdx.x] - tsum);
#pragma unroll
    for (int k = 0; k < 8; ++k) {
        int i = base + k;
        if (i < n) {
            out[i] = running;
            if (cursor2) cursor2[i] = running;
        }
        running += v[k];
    }
    if (writeTotal && b == 0 && threadIdx.x == 0) out[n] = total;
}

// ---------------- A1: bucket histogram (+ fused global row histogram) ----------------
__global__ void __launch_bounds__(512) k_bhist(const int* __restrict__ rows,
                                               int* __restrict__ counts,
                                               int* __restrict__ rowcnt) {
    __shared__ int c[NBUCK];
    for (int i = threadIdx.x; i < NBUCK; i += 512) c[i] = 0;
    __syncthreads();
    int b0 = blockIdx.x * EPB;
    for (int i = threadIdx.x; i < EPB; i += 512) {
        int e = b0 + i;
        if (e < NNZ) {
            int r = rows[e];
            atomicAdd(&c[r / ROWS_PB], 1);
            atomicAdd(&rowcnt[r], 1);
        }
    }
    __syncthreads();
    for (int k = threadIdx.x; k < NBUCK; k += 512)
        counts[k * NB_A + blockIdx.x] = c[k];
}

// ---------------- A3: chunked scatter into bucket-ordered staging ----------------
// offs = exclusive-scanned counts matrix (k-major). Each (block,bucket) chunk is
// contiguous and written by exactly one block -> clean full-line evictions.
__global__ void __launch_bounds__(512) k_bscatter(
    const int* __restrict__ rows, const int* __restrict__ cols,
    const void* __restrict__ vals, const int* __restrict__ flags,
    const int* __restrict__ offs,
    u32* __restrict__ ecol, u16* __restrict__ eval) {
    __shared__ int base[NBUCK];
    __shared__ int rk[NBUCK];
    for (int i = threadIdx.x; i < NBUCK; i += 512) {
        base[i] = offs[i * NB_A + blockIdx.x];
        rk[i] = 0;
    }
    __syncthreads();
    int valF32 = flags[1];
    int b0 = blockIdx.x * EPB;
    for (int i = threadIdx.x; i < EPB; i += 512) {
        int e = b0 + i;
        if (e < NNZ) {
            int r = rows[e];
            int k = r / ROWS_PB;
            int rank = atomicAdd(&rk[k], 1);
            int p = base[k] + rank;
            u16 v = valF32 ? f2bf(((const float*)vals)[e]) : ((const u16*)vals)[e];
            ecol[p] = ((u32)(r - k * ROWS_PB) << 19) | (u32)cols[e];
            eval[p] = v;
        }
    }
}

// ---------------- B: per-bucket final CSR scatter with LDS cursors ----------------
// One workgroup owns one bucket: destinations span ~150KB, written by one XCD's
// L2 only -> lines fill before eviction. No global cursor atomics.
__global__ void __launch_bounds__(512) k_bsort(
    const int* __restrict__ row_ptr, const int* __restrict__ offs,
    const u32* __restrict__ ecol, const u16* __restrict__ eval,
    int* __restrict__ col_s, u16* __restrict__ val_s) {
    __shared__ int cur[ROWS_PB];
    int k = blockIdx.x;
    int rowbase = k * ROWS_PB;
    for (int i = threadIdx.x; i < ROWS_PB; i += 512) {
        int r = rowbase + i;
        cur[i] = (r < N_NODES) ? row_ptr[r] : NNZ;
    }
    __syncthreads();
    int s = offs[k * NB_A];
    int e = (k == NBUCK - 1) ? NNZ : offs[(k + 1) * NB_A];
    for (int j = s + threadIdx.x; j < e; j += 512) {
        u32 ec = ecol[j];
        int rl = (int)(ec >> 19);
        int p = atomicAdd(&cur[rl], 1);
        col_s[p] = (int)(ec & 0x7FFFFu);
        val_s[p] = eval[j];
    }
}

// ---------------- SpMM layer: one wave per row, lane = emb dim ----------------
__global__ void __launch_bounds__(256) k_spmm(
    const int* __restrict__ row_ptr, const int* __restrict__ col_s,
    const u16* __restrict__ val_s, const u16* __restrict__ ego_in,
    u16* __restrict__ ego_out, float* __restrict__ acc) {
    int row = __builtin_amdgcn_readfirstlane(
        (int)((blockIdx.x * blockDim.x + threadIdx.x) >> 6));
    int lane = threadIdx.x & 63;
    if (row >= N_NODES) return;
    int start = row_ptr[row];
    int end   = row_ptr[row + 1];
    float a = 0.f;
    int j = start;
    for (; j + 4 <= end; j += 4) {
        int c0 = col_s[j], c1 = col_s[j + 1], c2 = col_s[j + 2], c3 = col_s[j + 3];
        u16 w0 = val_s[j], w1 = val_s[j + 1], w2 = val_s[j + 2], w3 = val_s[j + 3];
        float x0 = bf2f(ego_in[c0 * EMB + lane]);
        float x1 = bf2f(ego_in[c1 * EMB + lane]);
        float x2 = bf2f(ego_in[c2 * EMB + lane]);
        float x3 = bf2f(ego_in[c3 * EMB + lane]);
        a += bf2f(w0) * x0;
        a += bf2f(w1) * x1;
        a += bf2f(w2) * x2;
        a += bf2f(w3) * x3;
    }
    for (; j < end; ++j) {
        a += bf2f(val_s[j]) * bf2f(ego_in[col_s[j] * EMB + lane]);
    }
    int o = row * EMB + lane;
    acc[o] += a;
    ego_out[o] = f2bf(a);
}

// ---------------- T2 fallback: CSR by permutation ----------------
__global__ void k_hist(const int* __restrict__ rows, int* __restrict__ cnt) {
    int e = blockIdx.x * blockDim.x + threadIdx.x;
    if (e < NNZ) atomicAdd(&cnt[rows[e]], 1);
}

__global__ void k_scatter_perm(const int* __restrict__ rows, int* __restrict__ cursor,
                               u32* __restrict__ perm) {
    int e = blockIdx.x * blockDim.x + threadIdx.x;
    if (e >= NNZ) return;
    int r = rows[e];
    int p = atomicAdd(&cursor[r], 1);
    perm[p] = (u32)e;
}

__global__ void __launch_bounds__(256) k_spmm_perm(
    const int* __restrict__ row_ptr, const u32* __restrict__ perm,
    const int* __restrict__ cols, const void* __restrict__ vals,
    const int* __restrict__ flags, const u16* __restrict__ ego_in,
    u16* __restrict__ ego_out, float* __restrict__ acc) {
    int row = __builtin_amdgcn_readfirstlane(
        (int)((blockIdx.x * blockDim.x + threadIdx.x) >> 6));
    int lane = threadIdx.x & 63;
    if (row >= N_NODES) return;
    int valF32 = flags[1];
    int start = row_ptr[row];
    int end   = row_ptr[row + 1];
    float a = 0.f;
    for (int j = start; j < end; ++j) {
        u32 eid = perm[j];
        int c = cols[eid];
        float w = valF32 ? ((const float*)vals)[eid] : bf2f(((const u16*)vals)[eid]);
        a += w * bf2f(ego_in[c * EMB + lane]);
    }
    int o = row * EMB + lane;
    acc[o] += a;
    ego_out[o] = f2bf(a);
}

// ---------------- T3 fallback: edge-parallel atomics ----------------
__global__ void __launch_bounds__(256) k_edge_atomic(
    const int* __restrict__ rows, const int* __restrict__ cols,
    const void* __restrict__ vals, const int* __restrict__ flags,
    const u16* __restrict__ ego, float* __restrict__ layer) {
    int t = blockIdx.x * blockDim.x + threadIdx.x;
    int e = t >> 4;
    if (e >= NNZ) return;
    int d4 = (t & 15) * 4;
    int r = rows[e], c = cols[e];
    float w = flags[1] ? ((const float*)vals)[e] : bf2f(((const u16*)vals)[e]);
    ushort4 x = *(const ushort4*)(ego + c * EMB + d4);
    float* dst = layer + r * EMB + d4;
    atomicAdd(dst + 0, w * bf2f(x.x));
    atomicAdd(dst + 1, w * bf2f(x.y));
    atomicAdd(dst + 2, w * bf2f(x.z));
    atomicAdd(dst + 3, w * bf2f(x.w));
}

__global__ void k_layer_fin(float* __restrict__ layer, float* __restrict__ acc,
                            u16* __restrict__ ego) {
    int t = blockIdx.x * blockDim.x + threadIdx.x;
    int e = t * 4;
    if (e >= TOTAL_ELEMS) return;
    float4 L = *(const float4*)(layer + e);
    float4 A = *(const float4*)(acc + e);
    A.x += L.x; A.y += L.y; A.z += L.z; A.w += L.w;
    *(float4*)(acc + e) = A;
    ushort4 o;
    o.x = f2bf(L.x); o.y = f2bf(L.y); o.z = f2bf(L.z); o.w = f2bf(L.w);
    *(ushort4*)(ego + e) = o;
    float4 z; z.x = 0.f; z.y = 0.f; z.z = 0.f; z.w = 0.f;
    *(float4*)(layer + e) = z;
}

// ---------------- finalize: out = (acc / 4) in output dtype ----------------
__global__ void k_final(const float* __restrict__ acc, const int* __restrict__ flags,
                        void* __restrict__ out) {
    int t = blockIdx.x * blockDim.x + threadIdx.x;
    int e = t * 4;
    if (e >= TOTAL_ELEMS) return;
    float4 f = *(const float4*)(acc + e);
    f.x *= 0.25f; f.y *= 0.25f; f.z *= 0.25f; f.w *= 0.25f;
    if (flags[0]) {
        *(float4*)((float*)out + e) = f;
    } else {
        ushort4 v;
        v.x = f2bf(f.x); v.y = f2bf(f.y); v.z = f2bf(f.z); v.w = f2bf(f.w);
        *(ushort4*)((u16*)out + e) = v;
    }
}

extern "C" void kernel_launch(void* const* d_in, const int* in_sizes, int n_in,
                              void* d_out, int out_size, void* d_ws, size_t ws_size,
                              hipStream_t stream) {
    const void* user = d_in[0];
    const void* item = d_in[1];
    const void* vals = d_in[2];
    const int*  rows = (const int*)d_in[3];
    const int*  cols = (const int*)d_in[4];

    char* ws = (char*)d_ws;
    int* flags = (int*)ws;

    const int initGrid = (TOTAL_ELEMS / 4 + 255) / 256;   // 18750
    const int edgeGrid = (NNZ + 255) / 256;                // 50000
    const int spmmGrid = (N_NODES * 64) / 256;             // 75000

    k_detect<<<1, 64, 0, stream>>>((const u16*)user, (const u16*)vals, flags);

    if (ws_size >= T0_NEED) {
        // ---- T0: bucketed split counting sort + CSR SpMM ----
        size_t off = FLAGS_SZ;
        int* rp    = (int*)(ws + off); off += RP_SZ;      // row cnt -> row_ptr (in place)
        int* bs1   = (int*)(ws + off); off += BS_SZ;
        int* bo1   = (int*)(ws + off); off += BS_SZ;
        int* cntm  = (int*)(ws + off); off += CNTM_SZ;    // count matrix -> offsets (in place)
        int* bs2   = (int*)(ws + off); off += BS_SZ;
        int* bo2   = (int*)(ws + off); off += BS_SZ;
        int* col_s = (int*)(ws + off); off += COL_SZ;
        u16* val_s = (u16*)(ws + off); off += VALSORT_SZ;
        char* big  = ws + off;                             // 115.2MB shared region
        u32* ecol  = (u32*)big;                            // staging (dead after k_bsort)
        u16* eval  = (u16*)(big + 51200000);
        float* acc = (float*)big;                          // live after k_init
        u16* ego1  = (u16*)(big + ACC_SZ);
        u16* ego0  = (u16*)d_out;

        hipMemsetAsync(rp, 0, N_NODES * sizeof(int), stream);
        k_bhist<<<NB_A, 512, 0, stream>>>(rows, cntm, rp);
        // row_ptr scan (in place over rp)
        k_scan_reduce<<<SCAN_NB, 256, 0, stream>>>(rp, bs1, N_NODES);
        k_scan_block<<<1, 256, 0, stream>>>(bs1, bo1, SCAN_NB);
        k_scan_down<<<SCAN_NB, 256, 0, stream>>>(rp, bo1, rp, (int*)0, N_NODES, NNZ, 1);
        // count-matrix scan (in place over cntm)
        k_scan_reduce<<<SCAN2_NB, 256, 0, stream>>>(cntm, bs2, CNT_LEN);
        k_scan_block<<<1, 256, 0, stream>>>(bs2, bo2, SCAN2_NB);
        k_scan_down<<<SCAN2_NB, 256, 0, stream>>>(cntm, bo2, cntm, (int*)0, CNT_LEN, 0, 0);

        k_bscatter<<<NB_A, 512, 0, stream>>>(rows, cols, vals, flags, cntm, ecol, eval);
        k_bsort<<<NBUCK, 512, 0, stream>>>(rp, cntm, ecol, eval, col_s, val_s);

        k_init<<<initGrid, 256, 0, stream>>>(user, item, flags, ego0, acc);   // after k_bsort: acc aliases staging
        k_spmm<<<spmmGrid, 256, 0, stream>>>(rp, col_s, val_s, ego0, ego1, acc);
        k_spmm<<<spmmGrid, 256, 0, stream>>>(rp, col_s, val_s, ego1, ego0, acc);
        k_spmm<<<spmmGrid, 256, 0, stream>>>(rp, col_s, val_s, ego0, ego1, acc);
        k_final<<<initGrid, 256, 0, stream>>>(acc, flags, d_out);
    } else if (ws_size >= T2_NEED) {
        // ---- T2: permutation CSR ----
        size_t off = FLAGS_SZ;
        float* acc = (float*)(ws + off); off += ACC_SZ;
        u16* ego0 = (u16*)d_out;
        u16* ego1 = (u16*)(ws + off); off += EGO_SZ;
        int* row_ptr = (int*)(ws + off); off += RP_SZ;
        int* cursor  = (int*)(ws + off); off += RP_SZ;
        int* bsums   = (int*)(ws + off); off += BS_SZ;
        int* boffs   = (int*)(ws + off); off += BS_SZ;
        u32* perm    = (u32*)(ws + off); off += PERM_SZ;

        hipMemsetAsync(cursor, 0, N_NODES * sizeof(int), stream);
        k_init<<<initGrid, 256, 0, stream>>>(user, item, flags, ego0, acc);
        k_hist<<<edgeGrid, 256, 0, stream>>>(rows, cursor);
        k_scan_reduce<<<SCAN_NB, 256, 0, stream>>>(cursor, bsums, N_NODES);
        k_scan_block<<<1, 256, 0, stream>>>(bsums, boffs, SCAN_NB);
        k_scan_down<<<SCAN_NB, 256, 0, stream>>>(cursor, boffs, row_ptr, cursor,
                                                 N_NODES, NNZ, 1);
        k_scatter_perm<<<edgeGrid, 256, 0, stream>>>(rows, cursor, perm);
        k_spmm_perm<<<spmmGrid, 256, 0, stream>>>(row_ptr, perm, cols, vals, flags,
                                                  ego0, ego1, acc);
        k_spmm_perm<<<spmmGrid, 256, 0, stream>>>(row_ptr, perm, cols, vals, flags,
                                                  ego1, ego0, acc);
        k_spmm_perm<<<spmmGrid, 256, 0, stream>>>(row_ptr, perm, cols, vals, flags,
                                                  ego0, ego1, acc);
        k_final<<<initGrid, 256, 0, stream>>>(acc, flags, d_out);
    } else {
        // ---- T3: edge-parallel atomics, minimal footprint ----
        size_t off = FLAGS_SZ;
        float* acc   = (float*)(ws + off); off += ACC_SZ;
        float* layer = (float*)(ws + off); off += LAYER_SZ;
        u16* ego = (u16*)d_out;
        hipMemsetAsync(layer, 0, LAYER_SZ, stream);
        k_init<<<initGrid, 256, 0, stream>>>(user, item, flags, ego, acc);
        const int atomGrid = (NNZ * 16) / 256;
        for (int l = 0; l < 3; ++l) {
            k_edge_atomic<<<atomGrid, 256, 0, stream>>>(rows, cols, vals, flags, ego, layer);
            k_layer_fin<<<initGrid, 256, 0, stream>>>(layer, acc, ego);
        }
        k_final<<<initGrid, 256, 0, stream>>>(acc, flags, d_out);
    }
}